// Round 8
// baseline (214.602 us; speedup 1.0000x reference)
//
#include <hip/hip_runtime.h>

// ---------------------------------------------------------------------------
// AgglutinativeAttention: hs->QKV proj -> morpho-biased softmax attn -> out proj
// B=4 S=1024 H=1024 NH=16 HD=64.  bf16 MFMA throughout.
// R16: two local fixes on the R8/R15 baseline (211 us):
//  (a) gemm<1> epilogue: was 16B-scattered f32x4 stores (16 rows/instr,
//      4x line amplification risk, same family as R9's 8.8x). Now per-wave
//      LDS transpose (32KB staging LDS reused post-loop) -> 4x256B
//      contiguous segments per store instruction.
//  (b) k_attn: K/V LDS double-buffered -> ONE __syncthreads per K-chunk
//      (was 2; 32->17 barrier drains). Write next chunk to buf^1 overlaps
//      compute on buf; end-of-iter barrier separates iter kc+1 writes from
//      iter kc reads; pre-PV lgkmcnt(0) drains writes. LDS 49KB -> 3
//      blocks/CU = 12 waves (R15: occupancy-insensitive in this range).
//      K-loop math and numerics untouched.
// ---------------------------------------------------------------------------

#define QSCALE 0.18033688011112042f   /* 0.125 * log2(e) */
#define CB0    1.0820212806667225f    /* 0.75 * log2(e) */
#define CB1    0.5193702147200268f    /* 0.36 * log2(e) */
#define VERB2  2.8853900817779268f    /* 2.0  * log2(e) */

typedef float  f32x4   __attribute__((ext_vector_type(4)));
typedef short  s16x8   __attribute__((ext_vector_type(8)));
typedef unsigned short u16x4 __attribute__((ext_vector_type(4)));
typedef unsigned short u16x8 __attribute__((ext_vector_type(8)));

#if __has_builtin(__builtin_amdgcn_exp2f)
#define EXP2F(x) __builtin_amdgcn_exp2f(x)
#else
#define EXP2F(x) exp2f(x)
#endif

__device__ __forceinline__ unsigned short f2bf(float f) {
  union { float f; unsigned u; } a; a.f = f;
  unsigned r = a.u + 0x7fffu + ((a.u >> 16) & 1u);   // RNE
  return (unsigned short)(r >> 16);
}

__device__ __forceinline__ void async16(const void* g, void* l) {
  __builtin_amdgcn_global_load_lds(
      (const __attribute__((address_space(1))) unsigned int*)g,
      (__attribute__((address_space(3))) unsigned int*)l, 16, 0, 0);
}

// ---------------- fused prep: cvt (2048) | weight-T x4 (1024) | bias (16) ---
__global__ __launch_bounds__(256) void k_prep(
    const float* __restrict__ hs, unsigned short* __restrict__ hsb,
    const float* __restrict__ Wq, const float* __restrict__ Wk,
    const float* __restrict__ Wv, const float* __restrict__ Wo,
    unsigned short* __restrict__ Wt, const int* __restrict__ mt,
    float* __restrict__ colbias, int* __restrict__ nearest) {
  __shared__ float t[64 * 68];
  int bx = blockIdx.x, tid = threadIdx.x;
  if (bx < 2048) {
    int i = (bx * 256 + tid) * 8;
    float4 v0 = *(const float4*)(hs + i);
    float4 v1 = *(const float4*)(hs + i + 4);
    u16x8 o;
    o[0] = f2bf(v0.x); o[1] = f2bf(v0.y); o[2] = f2bf(v0.z); o[3] = f2bf(v0.w);
    o[4] = f2bf(v1.x); o[5] = f2bf(v1.y); o[6] = f2bf(v1.z); o[7] = f2bf(v1.w);
    *(u16x8*)(hsb + i) = o;
  } else if (bx < 3072) {
    int w = (bx - 2048) >> 8, tt = (bx - 2048) & 255;
    const float* W = (w == 0) ? Wq : (w == 1) ? Wk : (w == 2) ? Wv : Wo;
    unsigned short* Wd = Wt + (size_t)w * 1048576;
    int n0 = (tt & 15) * 64, k0 = (tt >> 4) * 64;
    int r = tid >> 2, c0 = (tid & 3) * 16;
    const float* src = &W[(k0 + r) * 1024 + n0 + c0];
    float4 a0 = *(const float4*)(src + 0);
    float4 a1 = *(const float4*)(src + 4);
    float4 a2 = *(const float4*)(src + 8);
    float4 a3 = *(const float4*)(src + 12);
    *(float4*)&t[r * 68 + c0 + 0]  = a0;
    *(float4*)&t[r * 68 + c0 + 4]  = a1;
    *(float4*)&t[r * 68 + c0 + 8]  = a2;
    *(float4*)&t[r * 68 + c0 + 12] = a3;
    __syncthreads();
    u16x8 o0, o1;
#pragma unroll
    for (int j = 0; j < 8; j++) {
      o0[j] = f2bf(t[(c0 + j) * 68 + r]);
      o1[j] = f2bf(t[(c0 + 8 + j) * 68 + r]);
    }
    *(u16x8*)&Wd[(n0 + r) * 1024 + k0 + c0]     = o0;
    *(u16x8*)&Wd[(n0 + r) * 1024 + k0 + c0 + 8] = o1;
  } else {
    int i = bx - 3072;
    int b = i >> 2;
    int* sm = (int*)t;
    for (int j = tid; j < 1024; j += 256) sm[j] = mt[b * 1024 + j];
    __syncthreads();
    int q = (i & 3) * 256 + tid;
    int best = 1 << 30, bj = -1;
    for (int j = 0; j < 1024; ++j) {
      int d = (q > j) ? (q - j) : (j - q);
      int dd = (sm[j] == 2) ? d : (1 << 30);
      if (dd < best) { best = dd; bj = j; }
    }
    nearest[b * 1024 + q] = bj;
    int m = sm[q];
    colbias[b * 1024 + q] = CB0 * (m == 0) + CB1 * (m == 1);
  }
}

// ---------------- MFMA GEMM, BK=64, XOR-swizzled staging --------------------
// MODE 0: fused QKV, grid (24,32), 128x128 tiles (3 blocks/CU co-resident).
// MODE 1: out-proj, grid (8,64), 64x128 tiles (2 blocks/CU); epilogue via
//         per-wave LDS transpose -> contiguous 256B-per-row fp32 stores.
template <int MODE>
__global__ __launch_bounds__(256) void k_gemm(
    const unsigned short* __restrict__ A,
    const unsigned short* __restrict__ WtBase,
    const float* __restrict__ bias0, const float* __restrict__ bias1,
    const float* __restrict__ bias2,
    unsigned short* __restrict__ outB, unsigned short* __restrict__ outV,
    float* __restrict__ outF) {
  constexpr int TM = (MODE == 0) ? 128 : 64;
  constexpr int NI = (MODE == 0) ? 4 : 2;       // m-fragments per wave
  constexpr int RA = TM / 4;                    // A rows staged per wave
  __shared__ unsigned short SMEM[16384];        // 32 KB flat
  unsigned short* As = SMEM;
  unsigned short* Bs = SMEM + TM * 64;
  int tid = threadIdx.x, wid = tid >> 6, lane = tid & 63;
  int c = lane & 15, quad = lane >> 4;
  int m0, wsel, n0;
  const unsigned short* Bt;
  const float* bias;
  if (MODE == 0) {
    wsel = blockIdx.x >> 3;
    n0 = (blockIdx.x & 7) * 128;
    m0 = blockIdx.y * 128;
    Bt = WtBase + wsel * 1048576;
    bias = (wsel == 0) ? bias0 : ((wsel == 1) ? bias1 : bias2);
  } else {
    wsel = 0;
    n0 = blockIdx.x * 128;
    m0 = blockIdx.y * 64;
    Bt = WtBase; bias = bias0;
  }
  int wm = (wid >> 1) * (16 * NI), wn = (wid & 1) * 64;
  int lr = lane >> 3, lc = lane & 7;
  int gcol = ((lc ^ lr) << 3);                  // XOR-swizzled 16B chunk
  const unsigned short* ga = A  + (size_t)(m0 + wid * RA + lr) * 1024 + gcol;
  const unsigned short* gb = Bt + (size_t)(n0 + wid * 32 + lr) * 1024 + gcol;
  unsigned short* lA = &As[(wid * RA) * 64];
  unsigned short* lB = &Bs[(wid * 32) * 64];

  f32x4 acc[NI][4];
#pragma unroll
  for (int i = 0; i < NI; i++)
#pragma unroll
    for (int j = 0; j < 4; j++) acc[i][j] = (f32x4){0.f, 0.f, 0.f, 0.f};

  bool sw = (MODE == 1) || (wsel != 2);         // swapped-operand (wave-uniform)

  for (int k0 = 0; k0 < 1024; k0 += 64) {
#pragma unroll
    for (int i = 0; i < RA / 8; i++) async16(ga + i * 8 * 1024 + k0, lA + i * 8 * 64);
#pragma unroll
    for (int j = 0; j < 4; j++)      async16(gb + j * 8 * 1024 + k0, lB + j * 8 * 64);
    __syncthreads();                             // staging visible (vmcnt drained)
#pragma unroll
    for (int ks = 0; ks < 2; ks++) {
      s16x8 af[NI], bf[4];
#pragma unroll
      for (int i = 0; i < NI; i++)
        af[i] = *(const s16x8*)&As[(wm + i * 16 + c) * 64 + (((ks * 4 + quad) ^ (c & 7)) << 3)];
#pragma unroll
      for (int j = 0; j < 4; j++)
        bf[j] = *(const s16x8*)&Bs[(wn + j * 16 + c) * 64 + (((ks * 4 + quad) ^ (c & 7)) << 3)];
      if (sw) {
#pragma unroll
        for (int i = 0; i < NI; i++)
#pragma unroll
          for (int j = 0; j < 4; j++)
            acc[i][j] = __builtin_amdgcn_mfma_f32_16x16x32_bf16(bf[j], af[i], acc[i][j], 0, 0, 0);
      } else {
#pragma unroll
        for (int i = 0; i < NI; i++)
#pragma unroll
          for (int j = 0; j < 4; j++)
            acc[i][j] = __builtin_amdgcn_mfma_f32_16x16x32_bf16(af[i], bf[j], acc[i][j], 0, 0, 0);
      }
    }
    __syncthreads();                             // all reads done before re-stage
  }

  if (MODE == 1) {
    // Per-wave LDS transpose -> contiguous stores. Wave tile: 32 tok x 64 col
    // fp32 (8KB); LDS image [tok][16 chunks of 16B], chunk ^ (tok&15).
    float* Wf = (float*)SMEM + wid * 2048;
#pragma unroll
    for (int j = 0; j < 4; j++) {
      int colb = n0 + wn + j * 16 + quad * 4;
      f32x4 bvv = *(const f32x4*)&bias[colb];
#pragma unroll
      for (int i = 0; i < NI; i++) {
        f32x4 v = acc[i][j] + bvv;
        int tokl = i * 16 + c;                   // 0..31 (tokl&15 == c)
        int chs = (j * 4 + quad) ^ c;            // 16B chunk 0..15, swizzled
        *(f32x4*)&Wf[tokl * 64 + chs * 4] = v;
      }
    }
    __asm__ volatile("s_waitcnt lgkmcnt(0)" ::: "memory");
    int t4 = lane >> 4, chl = lane & 15;
#pragma unroll
    for (int t = 0; t < 8; t++) {
      int tokl = t * 4 + t4;
      int chs = chl ^ (tokl & 15);
      f32x4 v = *(const f32x4*)&Wf[tokl * 64 + chs * 4];
      *(f32x4*)&outF[(size_t)(m0 + wm + tokl) * 1024 + n0 + wn + chl * 4] = v;
    }
  } else if (wsel == 2) {
    // V normal order: row=token (4-contig) -> u16x4 into [b,h,d,s]
#pragma unroll
    for (int j = 0; j < 4; j++) {
      int col = n0 + wn + j * 16 + c;
      float bv = bias[col];
      int h = col >> 6, d = col & 63;
#pragma unroll
      for (int i = 0; i < NI; i++) {
        int row = m0 + wm + i * 16 + quad * 4;
        int bb = row >> 10, s = row & 1023;
        u16x4 pk;
#pragma unroll
        for (int r = 0; r < 4; r++) pk[r] = f2bf(acc[i][j][r] + bv);
        *(u16x4*)&outV[(size_t)(((bb * 16 + h) * 64 + d)) * 1024 + s] = pk;
      }
    }
  } else {
    // Q/K swapped: row=feature (4-contig), col=token -> u16x4 into [b,h,s,d]
    float sc = (wsel == 0) ? QSCALE : 1.0f;
#pragma unroll
    for (int j = 0; j < 4; j++) {
      int colb = n0 + wn + j * 16 + quad * 4;
      f32x4 bvv = *(const f32x4*)&bias[colb];
      int h = colb >> 6, d0 = colb & 63;
#pragma unroll
      for (int i = 0; i < NI; i++) {
        int s_tok = m0 + wm + i * 16 + c;
        int bb = s_tok >> 10, s = s_tok & 1023;
        u16x4 pk;
#pragma unroll
        for (int r = 0; r < 4; r++) pk[r] = f2bf((acc[i][j][r] + bvv[r]) * sc);
        *(u16x4*)&outB[(size_t)wsel * 4194304 + (((bb * 16 + h) * 1024 + s) * 64) + d0] = pk;
      }
    }
  }
}

// ---------------- Flash attention, 16x16x32 MFMA, streaming softmax ---------
// grid (bh=64, qt=16): 4 waves/block, 16 q-rows/wave. K/V LDS double-buffered
// -> 1 barrier/chunk: write next chunk to buf^1 overlaps compute on buf.
// LDS 49KB -> 3 blocks/CU (12 waves). Same-bh blocks on one XCD (bh mod 8).
__global__ __launch_bounds__(256) void k_attn(
    const unsigned short* __restrict__ Q, const unsigned short* __restrict__ K,
    const unsigned short* __restrict__ Vt, const float* __restrict__ colbias,
    const int* __restrict__ nearest, unsigned short* __restrict__ AO) {
  __shared__ unsigned short Ks[2][64 * 72];  // [buf][key][d]
  __shared__ unsigned short Vs[2][64 * 72];  // [buf][d][key]
  __shared__ unsigned short Ps[4][16 * 72];  // per-wave [q][key]
  __shared__ float Cb[1024];
  int tid = threadIdx.x, wid = tid >> 6, lane = tid & 63;
  int c = lane & 15, quad = lane >> 4;
  int bh = blockIdx.x, qt = blockIdx.y;
  int b = bh >> 4, head = bh & 15;
  int q0 = qt * 64, wq = wid * 16;
  const unsigned short* Qg = Q  + (size_t)(bh * 1024 + q0 + wq) * 64;
  const unsigned short* Kg = K  + (size_t)bh * 1024 * 64;
  const unsigned short* Vg = Vt + (size_t)bh * 64 * 1024;

  *(float4*)&Cb[tid * 4] = *(const float4*)&colbias[b * 1024 + tid * 4];

  s16x8 qf[2];
#pragma unroll
  for (int ks = 0; ks < 2; ks++)
    qf[ks] = *(const s16x8*)&Qg[c * 64 + ks * 32 + quad * 8];

  int nq = nearest[b * 1024 + q0 + wq + c];

  f32x4 o[4];
#pragma unroll
  for (int j = 0; j < 4; j++) o[j] = (f32x4){0.f, 0.f, 0.f, 0.f};
  float lrun = 0.f;

  int srow = tid >> 3, scol8 = (tid & 7) * 8;

  u16x8 kr[2], vr[2];
  // chunk 0 -> regs -> buf0
#pragma unroll
  for (int it = 0; it < 2; ++it) {
    int r2 = it * 32 + srow;
    kr[it] = *(const u16x8*)&Kg[r2 * 64 + scol8];
    vr[it] = *(const u16x8*)&Vg[r2 * 1024 + scol8];
  }
#pragma unroll
  for (int it = 0; it < 2; ++it) {
    int r2 = it * 32 + srow;
    *(u16x8*)&Ks[0][r2 * 72 + scol8] = kr[it];
    *(u16x8*)&Vs[0][r2 * 72 + scol8] = vr[it];
  }
  // chunk 1 -> regs
#pragma unroll
  for (int it = 0; it < 2; ++it) {
    int r2 = it * 32 + srow;
    kr[it] = *(const u16x8*)&Kg[(64 + r2) * 64 + scol8];
    vr[it] = *(const u16x8*)&Vg[r2 * 1024 + 64 + scol8];
  }
  __syncthreads();   // buf0 + Cb visible

  for (int kc = 0; kc < 16; ++kc) {
    int cur = kc & 1;
    // write next chunk (regs) into the other buffer; overlaps compute below.
    // Safe: buf[cur^1] reads (iter kc-1) are behind the last barrier.
    if (kc < 15) {
#pragma unroll
      for (int it = 0; it < 2; ++it) {
        int r2 = it * 32 + srow;
        *(u16x8*)&Ks[cur ^ 1][r2 * 72 + scol8] = kr[it];
        *(u16x8*)&Vs[cur ^ 1][r2 * 72 + scol8] = vr[it];
      }
    }
    if (kc < 14) {
#pragma unroll
      for (int it = 0; it < 2; ++it) {
        int r2 = it * 32 + srow;
        kr[it] = *(const u16x8*)&Kg[((kc + 2) * 64 + r2) * 64 + scol8];
        vr[it] = *(const u16x8*)&Vg[r2 * 1024 + (kc + 2) * 64 + scol8];
      }
    }

    // S^T = K . Q^T : st[mt] (key = mt*16+quad*4+r, q = c)
    f32x4 st[4];
#pragma unroll
    for (int mt = 0; mt < 4; mt++) st[mt] = (f32x4){0.f, 0.f, 0.f, 0.f};
#pragma unroll
    for (int mt = 0; mt < 4; mt++)
#pragma unroll
      for (int ks = 0; ks < 2; ks++) {
        s16x8 a = *(const s16x8*)&Ks[cur][(mt * 16 + c) * 72 + ks * 32 + quad * 8];
        st[mt] = __builtin_amdgcn_mfma_f32_16x16x32_bf16(a, qf[ks], st[mt], 0, 0, 0);
      }

    // rare verb-bias fixup: nq lands in this chunk for at most one element
    if (__any((nq >> 6) == kc)) {
#pragma unroll
      for (int mt = 0; mt < 4; mt++)
#pragma unroll
        for (int r = 0; r < 4; r++)
          if (kc * 64 + mt * 16 + quad * 4 + r == nq) st[mt][r] += VERB2;
    }

    // hot path: cb add + exp2 + v_perm truncate-pack; l from packed values
#pragma unroll
    for (int mt = 0; mt < 4; mt++) {
      f32x4 cb = *(const f32x4*)&Cb[kc * 64 + mt * 16 + quad * 4];
      float e0 = EXP2F(st[mt][0] + cb[0]);
      float e1 = EXP2F(st[mt][1] + cb[1]);
      float e2 = EXP2F(st[mt][2] + cb[2]);
      float e3 = EXP2F(st[mt][3] + cb[3]);
      unsigned p01 = __builtin_amdgcn_perm(__float_as_uint(e1), __float_as_uint(e0), 0x07060302u);
      unsigned p23 = __builtin_amdgcn_perm(__float_as_uint(e3), __float_as_uint(e2), 0x07060302u);
      lrun += __uint_as_float(p01 << 16) + __uint_as_float(p01 & 0xffff0000u)
            + __uint_as_float(p23 << 16) + __uint_as_float(p23 & 0xffff0000u);
      uint2 pk; pk.x = p01; pk.y = p23;
      *(uint2*)&Ps[wid][c * 72 + mt * 16 + quad * 4] = pk;
    }
    // drains Ps writes AND the next-chunk K/V writes before PV reads & barrier
    __asm__ volatile("s_waitcnt lgkmcnt(0)" ::: "memory");

    // O += (P . V) computed SWAPPED: o[ntd] rows = d, cols = q
#pragma unroll
    for (int ks = 0; ks < 2; ks++) {
      s16x8 pa = *(const s16x8*)&Ps[wid][c * 72 + ks * 32 + quad * 8];
#pragma unroll
      for (int ntd = 0; ntd < 4; ntd++) {
        s16x8 vb = *(const s16x8*)&Vs[cur][(ntd * 16 + c) * 72 + ks * 32 + quad * 8];
        o[ntd] = __builtin_amdgcn_mfma_f32_16x16x32_bf16(vb, pa, o[ntd], 0, 0, 0);
      }
    }
    __syncthreads();   // all reads of buf[cur] done; next iter may overwrite it
  }

  // l-reduction across quads; lane's own token = c -> no shuffle
  lrun += __shfl_xor(lrun, 16, 64);
  lrun += __shfl_xor(lrun, 32, 64);
  float linv = 1.0f / lrun;
  size_t row = (size_t)(b * 1024 + q0 + wq + c);
#pragma unroll
  for (int ntd = 0; ntd < 4; ntd++) {
    int d0 = ntd * 16 + quad * 4;
    u16x4 pk;
#pragma unroll
    for (int r = 0; r < 4; r++) pk[r] = f2bf(o[ntd][r] * linv);
    *(u16x4*)&AO[row * 1024 + head * 64 + d0] = pk;
  }
}

// ---------------------------------------------------------------------------
extern "C" void kernel_launch(void* const* d_in, const int* in_sizes, int n_in,
                              void* d_out, int out_size, void* d_ws, size_t ws_size,
                              hipStream_t stream) {
  const float* hs     = (const float*)d_in[0];
  const int*   morpho = (const int*)d_in[1];
  const float* Wq = (const float*)d_in[2];
  const float* bq = (const float*)d_in[3];
  const float* Wk = (const float*)d_in[4];
  const float* bk = (const float*)d_in[5];
  const float* Wv = (const float*)d_in[6];
  const float* bv = (const float*)d_in[7];
  const float* Wo = (const float*)d_in[8];
  const float* bo = (const float*)d_in[9];
  float* out = (float*)d_out;

  char* ws = (char*)d_ws;
  unsigned short* hsb = (unsigned short*)(ws);                    // 8 MB [4096][1024]
  unsigned short* Wt  = (unsigned short*)(ws + (8u << 20));       // 8 MB [4][1024][1024]
  unsigned short* Qb  = (unsigned short*)(ws + (16u << 20));      // Q +16MB, K +24MB
  unsigned short* Kb  = (unsigned short*)(ws + (24u << 20));
  unsigned short* Vtb = (unsigned short*)(ws + (40u << 20));      // 8 MB [B,NH,HD,S]
  float* colbias      = (float*)(ws + (48u << 20));               // 16 KB
  int*   nearestp     = (int*)(ws + (48u << 20) + (16u << 10));   // 16 KB
  unsigned short* AO  = hsb;  // reuse: hs_bf16 dead after QKV GEMM

  k_prep<<<3088, 256, 0, stream>>>(hs, hsb, Wq, Wk, Wv, Wo, Wt, morpho,
                                   colbias, nearestp);
  k_gemm<0><<<dim3(24, 32), 256, 0, stream>>>(hsb, Wt, bq, bk, bv, Qb, Vtb, nullptr);
  k_attn<<<dim3(64, 16), 256, 0, stream>>>(Qb, Kb, Vtb, colbias, nearestp, AO);
  k_gemm<1><<<dim3(8, 64), 256, 0, stream>>>(AO, Wt + 3 * 1048576, bo, nullptr, nullptr,
                                             nullptr, nullptr, out);
  (void)in_sizes; (void)n_in; (void)out_size; (void)ws_size; (void)Kb;
}

// Round 9
// 211.784 us; speedup vs baseline: 1.0133x; 1.0133x over previous
//
#include <hip/hip_runtime.h>

// ---------------------------------------------------------------------------
// AgglutinativeAttention: hs->QKV proj -> morpho-biased softmax attn -> out proj
// B=4 S=1024 H=1024 NH=16 HD=64.  bf16 MFMA throughout.
// R17: k_attn LDS bank-conflict fix. R16's counters showed k_attn at 44.1us
//      with SQ_LDS_BANK_CONFLICT=5.77M (~9.4us/CU of serialization), while
//      k_gemm's XOR-swizzled ds_read_b128 pattern measures 0. The attn tiles
//      used 72-short padded rows (4-bank/row rotation -> bank = 4(c+quad),
//      multi-way). Now all attn LDS tiles use the GEMM-proven layout:
//      128B rows + chunk^(row&7) XOR swizzle on both write and read
//      (Ks/Vs staging, Ps pack+read). LDS 50.2->44KB. Numerics untouched.
//      Also: gemm<1> epilogue reverted to R8's direct f32x4 stores (R16's
//      speculative LDS transpose is the other suspect in the +3.5us).
// ---------------------------------------------------------------------------

#define QSCALE 0.18033688011112042f   /* 0.125 * log2(e) */
#define CB0    1.0820212806667225f    /* 0.75 * log2(e) */
#define CB1    0.5193702147200268f    /* 0.36 * log2(e) */
#define VERB2  2.8853900817779268f    /* 2.0  * log2(e) */

typedef float  f32x4   __attribute__((ext_vector_type(4)));
typedef short  s16x8   __attribute__((ext_vector_type(8)));
typedef unsigned short u16x4 __attribute__((ext_vector_type(4)));
typedef unsigned short u16x8 __attribute__((ext_vector_type(8)));

#if __has_builtin(__builtin_amdgcn_exp2f)
#define EXP2F(x) __builtin_amdgcn_exp2f(x)
#else
#define EXP2F(x) exp2f(x)
#endif

__device__ __forceinline__ unsigned short f2bf(float f) {
  union { float f; unsigned u; } a; a.f = f;
  unsigned r = a.u + 0x7fffu + ((a.u >> 16) & 1u);   // RNE
  return (unsigned short)(r >> 16);
}

__device__ __forceinline__ void async16(const void* g, void* l) {
  __builtin_amdgcn_global_load_lds(
      (const __attribute__((address_space(1))) unsigned int*)g,
      (__attribute__((address_space(3))) unsigned int*)l, 16, 0, 0);
}

// ---------------- fused prep: cvt (2048) | weight-T x4 (1024) | bias (16) ---
__global__ __launch_bounds__(256) void k_prep(
    const float* __restrict__ hs, unsigned short* __restrict__ hsb,
    const float* __restrict__ Wq, const float* __restrict__ Wk,
    const float* __restrict__ Wv, const float* __restrict__ Wo,
    unsigned short* __restrict__ Wt, const int* __restrict__ mt,
    float* __restrict__ colbias, int* __restrict__ nearest) {
  __shared__ float t[64 * 68];
  int bx = blockIdx.x, tid = threadIdx.x;
  if (bx < 2048) {
    int i = (bx * 256 + tid) * 8;
    float4 v0 = *(const float4*)(hs + i);
    float4 v1 = *(const float4*)(hs + i + 4);
    u16x8 o;
    o[0] = f2bf(v0.x); o[1] = f2bf(v0.y); o[2] = f2bf(v0.z); o[3] = f2bf(v0.w);
    o[4] = f2bf(v1.x); o[5] = f2bf(v1.y); o[6] = f2bf(v1.z); o[7] = f2bf(v1.w);
    *(u16x8*)(hsb + i) = o;
  } else if (bx < 3072) {
    int w = (bx - 2048) >> 8, tt = (bx - 2048) & 255;
    const float* W = (w == 0) ? Wq : (w == 1) ? Wk : (w == 2) ? Wv : Wo;
    unsigned short* Wd = Wt + (size_t)w * 1048576;
    int n0 = (tt & 15) * 64, k0 = (tt >> 4) * 64;
    int r = tid >> 2, c0 = (tid & 3) * 16;
    const float* src = &W[(k0 + r) * 1024 + n0 + c0];
    float4 a0 = *(const float4*)(src + 0);
    float4 a1 = *(const float4*)(src + 4);
    float4 a2 = *(const float4*)(src + 8);
    float4 a3 = *(const float4*)(src + 12);
    *(float4*)&t[r * 68 + c0 + 0]  = a0;
    *(float4*)&t[r * 68 + c0 + 4]  = a1;
    *(float4*)&t[r * 68 + c0 + 8]  = a2;
    *(float4*)&t[r * 68 + c0 + 12] = a3;
    __syncthreads();
    u16x8 o0, o1;
#pragma unroll
    for (int j = 0; j < 8; j++) {
      o0[j] = f2bf(t[(c0 + j) * 68 + r]);
      o1[j] = f2bf(t[(c0 + 8 + j) * 68 + r]);
    }
    *(u16x8*)&Wd[(n0 + r) * 1024 + k0 + c0]     = o0;
    *(u16x8*)&Wd[(n0 + r) * 1024 + k0 + c0 + 8] = o1;
  } else {
    int i = bx - 3072;
    int b = i >> 2;
    int* sm = (int*)t;
    for (int j = tid; j < 1024; j += 256) sm[j] = mt[b * 1024 + j];
    __syncthreads();
    int q = (i & 3) * 256 + tid;
    int best = 1 << 30, bj = -1;
    for (int j = 0; j < 1024; ++j) {
      int d = (q > j) ? (q - j) : (j - q);
      int dd = (sm[j] == 2) ? d : (1 << 30);
      if (dd < best) { best = dd; bj = j; }
    }
    nearest[b * 1024 + q] = bj;
    int m = sm[q];
    colbias[b * 1024 + q] = CB0 * (m == 0) + CB1 * (m == 1);
  }
}

// ---------------- MFMA GEMM, BK=64, XOR-swizzled staging --------------------
// MODE 0: fused QKV, grid (24,32), 128x128 tiles (3 blocks/CU co-resident).
// MODE 1: out-proj, grid (8,64), 64x128 tiles (2 blocks/CU co-resident).
template <int MODE>
__global__ __launch_bounds__(256) void k_gemm(
    const unsigned short* __restrict__ A,
    const unsigned short* __restrict__ WtBase,
    const float* __restrict__ bias0, const float* __restrict__ bias1,
    const float* __restrict__ bias2,
    unsigned short* __restrict__ outB, unsigned short* __restrict__ outV,
    float* __restrict__ outF) {
  constexpr int TM = (MODE == 0) ? 128 : 64;
  constexpr int NI = (MODE == 0) ? 4 : 2;       // m-fragments per wave
  constexpr int RA = TM / 4;                    // A rows staged per wave
  __shared__ unsigned short As[TM * 64];
  __shared__ unsigned short Bs[128 * 64];
  int tid = threadIdx.x, wid = tid >> 6, lane = tid & 63;
  int c = lane & 15, quad = lane >> 4;
  int m0, wsel, n0;
  const unsigned short* Bt;
  const float* bias;
  if (MODE == 0) {
    wsel = blockIdx.x >> 3;
    n0 = (blockIdx.x & 7) * 128;
    m0 = blockIdx.y * 128;
    Bt = WtBase + wsel * 1048576;
    bias = (wsel == 0) ? bias0 : ((wsel == 1) ? bias1 : bias2);
  } else {
    wsel = 0;
    n0 = blockIdx.x * 128;
    m0 = blockIdx.y * 64;
    Bt = WtBase; bias = bias0;
  }
  int wm = (wid >> 1) * (16 * NI), wn = (wid & 1) * 64;
  int lr = lane >> 3, lc = lane & 7;
  int gcol = ((lc ^ lr) << 3);                  // XOR-swizzled 16B chunk
  const unsigned short* ga = A  + (size_t)(m0 + wid * RA + lr) * 1024 + gcol;
  const unsigned short* gb = Bt + (size_t)(n0 + wid * 32 + lr) * 1024 + gcol;
  unsigned short* lA = &As[(wid * RA) * 64];
  unsigned short* lB = &Bs[(wid * 32) * 64];

  f32x4 acc[NI][4];
#pragma unroll
  for (int i = 0; i < NI; i++)
#pragma unroll
    for (int j = 0; j < 4; j++) acc[i][j] = (f32x4){0.f, 0.f, 0.f, 0.f};

  bool sw = (MODE == 1) || (wsel != 2);         // swapped-operand (wave-uniform)

  for (int k0 = 0; k0 < 1024; k0 += 64) {
#pragma unroll
    for (int i = 0; i < RA / 8; i++) async16(ga + i * 8 * 1024 + k0, lA + i * 8 * 64);
#pragma unroll
    for (int j = 0; j < 4; j++)      async16(gb + j * 8 * 1024 + k0, lB + j * 8 * 64);
    __syncthreads();                             // staging visible (vmcnt drained)
#pragma unroll
    for (int ks = 0; ks < 2; ks++) {
      s16x8 af[NI], bf[4];
#pragma unroll
      for (int i = 0; i < NI; i++)
        af[i] = *(const s16x8*)&As[(wm + i * 16 + c) * 64 + (((ks * 4 + quad) ^ (c & 7)) << 3)];
#pragma unroll
      for (int j = 0; j < 4; j++)
        bf[j] = *(const s16x8*)&Bs[(wn + j * 16 + c) * 64 + (((ks * 4 + quad) ^ (c & 7)) << 3)];
      if (sw) {
#pragma unroll
        for (int i = 0; i < NI; i++)
#pragma unroll
          for (int j = 0; j < 4; j++)
            acc[i][j] = __builtin_amdgcn_mfma_f32_16x16x32_bf16(bf[j], af[i], acc[i][j], 0, 0, 0);
      } else {
#pragma unroll
        for (int i = 0; i < NI; i++)
#pragma unroll
          for (int j = 0; j < 4; j++)
            acc[i][j] = __builtin_amdgcn_mfma_f32_16x16x32_bf16(af[i], bf[j], acc[i][j], 0, 0, 0);
      }
    }
    __syncthreads();                             // all reads done before re-stage
  }

  if (MODE == 1) {
    // swapped: row=feature (4-contig), col=token -> float4 stores
#pragma unroll
    for (int j = 0; j < 4; j++) {
      int colb = n0 + wn + j * 16 + quad * 4;
      f32x4 bvv = *(const f32x4*)&bias[colb];
#pragma unroll
      for (int i = 0; i < NI; i++) {
        int s_tok = m0 + wm + i * 16 + c;
        f32x4 v = acc[i][j] + bvv;
        *(f32x4*)&outF[(size_t)s_tok * 1024 + colb] = v;
      }
    }
  } else if (wsel == 2) {
    // V normal order: row=token (4-contig) -> u16x4 into [b,h,d,s]
#pragma unroll
    for (int j = 0; j < 4; j++) {
      int col = n0 + wn + j * 16 + c;
      float bv = bias[col];
      int h = col >> 6, d = col & 63;
#pragma unroll
      for (int i = 0; i < NI; i++) {
        int row = m0 + wm + i * 16 + quad * 4;
        int bb = row >> 10, s = row & 1023;
        u16x4 pk;
#pragma unroll
        for (int r = 0; r < 4; r++) pk[r] = f2bf(acc[i][j][r] + bv);
        *(u16x4*)&outV[(size_t)(((bb * 16 + h) * 64 + d)) * 1024 + s] = pk;
      }
    }
  } else {
    // Q/K swapped: row=feature (4-contig), col=token -> u16x4 into [b,h,s,d]
    float sc = (wsel == 0) ? QSCALE : 1.0f;
#pragma unroll
    for (int j = 0; j < 4; j++) {
      int colb = n0 + wn + j * 16 + quad * 4;
      f32x4 bvv = *(const f32x4*)&bias[colb];
      int h = colb >> 6, d0 = colb & 63;
#pragma unroll
      for (int i = 0; i < NI; i++) {
        int s_tok = m0 + wm + i * 16 + c;
        int bb = s_tok >> 10, s = s_tok & 1023;
        u16x4 pk;
#pragma unroll
        for (int r = 0; r < 4; r++) pk[r] = f2bf((acc[i][j][r] + bvv[r]) * sc);
        *(u16x4*)&outB[(size_t)wsel * 4194304 + (((bb * 16 + h) * 1024 + s) * 64) + d0] = pk;
      }
    }
  }
}

// ---------------- Flash attention, 16x16x32 MFMA, streaming softmax ---------
// grid (bh=64, qt=16): 4 waves/block, 16 q-rows/wave. K/V LDS double-buffered,
// 1 barrier/chunk. All LDS tiles: 128B rows + chunk^(row&7) XOR swizzle
// (k_gemm-proven 0-conflict pattern; replaces 72-short padding that measured
// 5.77M SQ_LDS_BANK_CONFLICT). LDS 44KB -> 3 blocks/CU.
__global__ __launch_bounds__(256) void k_attn(
    const unsigned short* __restrict__ Q, const unsigned short* __restrict__ K,
    const unsigned short* __restrict__ Vt, const float* __restrict__ colbias,
    const int* __restrict__ nearest, unsigned short* __restrict__ AO) {
  __shared__ unsigned short Ks[2][64 * 64];  // [buf][key][d]
  __shared__ unsigned short Vs[2][64 * 64];  // [buf][d][key]
  __shared__ unsigned short Ps[4][16 * 64];  // per-wave [q][key]
  __shared__ float Cb[1024];
  int tid = threadIdx.x, wid = tid >> 6, lane = tid & 63;
  int c = lane & 15, quad = lane >> 4;
  int bh = blockIdx.x, qt = blockIdx.y;
  int b = bh >> 4, head = bh & 15;
  int q0 = qt * 64, wq = wid * 16;
  const unsigned short* Qg = Q  + (size_t)(bh * 1024 + q0 + wq) * 64;
  const unsigned short* Kg = K  + (size_t)bh * 1024 * 64;
  const unsigned short* Vg = Vt + (size_t)bh * 64 * 1024;

  *(float4*)&Cb[tid * 4] = *(const float4*)&colbias[b * 1024 + tid * 4];

  s16x8 qf[2];
#pragma unroll
  for (int ks = 0; ks < 2; ks++)
    qf[ks] = *(const s16x8*)&Qg[c * 64 + ks * 32 + quad * 8];

  int nq = nearest[b * 1024 + q0 + wq + c];

  f32x4 o[4];
#pragma unroll
  for (int j = 0; j < 4; j++) o[j] = (f32x4){0.f, 0.f, 0.f, 0.f};
  float lrun = 0.f;

  int srow = tid >> 3;
  int swz8 = (((tid & 7) ^ (srow & 7)) << 3);   // swizzled 16B-chunk offset
  int scol8 = (tid & 7) * 8;                    // global column chunk (raw)
  const int cs = c & 7;

  u16x8 kr[2], vr[2];
  // chunk 0 -> regs -> buf0 (swizzled)
#pragma unroll
  for (int it = 0; it < 2; ++it) {
    int r2 = it * 32 + srow;
    kr[it] = *(const u16x8*)&Kg[r2 * 64 + scol8];
    vr[it] = *(const u16x8*)&Vg[r2 * 1024 + scol8];
  }
#pragma unroll
  for (int it = 0; it < 2; ++it) {
    int r2 = it * 32 + srow;
    *(u16x8*)&Ks[0][r2 * 64 + swz8] = kr[it];
    *(u16x8*)&Vs[0][r2 * 64 + swz8] = vr[it];
  }
  // chunk 1 -> regs
#pragma unroll
  for (int it = 0; it < 2; ++it) {
    int r2 = it * 32 + srow;
    kr[it] = *(const u16x8*)&Kg[(64 + r2) * 64 + scol8];
    vr[it] = *(const u16x8*)&Vg[r2 * 1024 + 64 + scol8];
  }
  __syncthreads();   // buf0 + Cb visible

  for (int kc = 0; kc < 16; ++kc) {
    int cur = kc & 1;
    // write next chunk (regs) into the other buffer; overlaps compute below.
    if (kc < 15) {
#pragma unroll
      for (int it = 0; it < 2; ++it) {
        int r2 = it * 32 + srow;
        *(u16x8*)&Ks[cur ^ 1][r2 * 64 + swz8] = kr[it];
        *(u16x8*)&Vs[cur ^ 1][r2 * 64 + swz8] = vr[it];
      }
    }
    if (kc < 14) {
#pragma unroll
      for (int it = 0; it < 2; ++it) {
        int r2 = it * 32 + srow;
        kr[it] = *(const u16x8*)&Kg[((kc + 2) * 64 + r2) * 64 + scol8];
        vr[it] = *(const u16x8*)&Vg[r2 * 1024 + (kc + 2) * 64 + scol8];
      }
    }

    // S^T = K . Q^T : st[mt] (key = mt*16+quad*4+r, q = c)
    f32x4 st[4];
#pragma unroll
    for (int mt = 0; mt < 4; mt++) st[mt] = (f32x4){0.f, 0.f, 0.f, 0.f};
#pragma unroll
    for (int mt = 0; mt < 4; mt++)
#pragma unroll
      for (int ks = 0; ks < 2; ks++) {
        s16x8 a = *(const s16x8*)&Ks[cur][(mt * 16 + c) * 64 + (((ks * 4 + quad) ^ cs) << 3)];
        st[mt] = __builtin_amdgcn_mfma_f32_16x16x32_bf16(a, qf[ks], st[mt], 0, 0, 0);
      }

    // rare verb-bias fixup: nq lands in this chunk for at most one element
    if (__any((nq >> 6) == kc)) {
#pragma unroll
      for (int mt = 0; mt < 4; mt++)
#pragma unroll
        for (int r = 0; r < 4; r++)
          if (kc * 64 + mt * 16 + quad * 4 + r == nq) st[mt][r] += VERB2;
    }

    // hot path: cb add + exp2 + v_perm truncate-pack; l from packed values
#pragma unroll
    for (int mt = 0; mt < 4; mt++) {
      f32x4 cb = *(const f32x4*)&Cb[kc * 64 + mt * 16 + quad * 4];
      float e0 = EXP2F(st[mt][0] + cb[0]);
      float e1 = EXP2F(st[mt][1] + cb[1]);
      float e2 = EXP2F(st[mt][2] + cb[2]);
      float e3 = EXP2F(st[mt][3] + cb[3]);
      unsigned p01 = __builtin_amdgcn_perm(__float_as_uint(e1), __float_as_uint(e0), 0x07060302u);
      unsigned p23 = __builtin_amdgcn_perm(__float_as_uint(e3), __float_as_uint(e2), 0x07060302u);
      lrun += __uint_as_float(p01 << 16) + __uint_as_float(p01 & 0xffff0000u)
            + __uint_as_float(p23 << 16) + __uint_as_float(p23 & 0xffff0000u);
      uint2 pk; pk.x = p01; pk.y = p23;
      // keys mt*16+quad*4..+4 -> raw 16B chunk 2mt+(quad>>1), half quad&1
      int chs = (2 * mt + (quad >> 1)) ^ cs;
      *(uint2*)&Ps[wid][c * 64 + chs * 8 + (quad & 1) * 4] = pk;
    }
    // drains Ps writes AND the next-chunk K/V writes before PV reads & barrier
    __asm__ volatile("s_waitcnt lgkmcnt(0)" ::: "memory");

    // O += (P . V) computed SWAPPED: o[ntd] rows = d, cols = q
#pragma unroll
    for (int ks = 0; ks < 2; ks++) {
      s16x8 pa = *(const s16x8*)&Ps[wid][c * 64 + (((ks * 4 + quad) ^ cs) << 3)];
#pragma unroll
      for (int ntd = 0; ntd < 4; ntd++) {
        s16x8 vb = *(const s16x8*)&Vs[cur][(ntd * 16 + c) * 64 + (((ks * 4 + quad) ^ cs) << 3)];
        o[ntd] = __builtin_amdgcn_mfma_f32_16x16x32_bf16(vb, pa, o[ntd], 0, 0, 0);
      }
    }
    __syncthreads();   // all reads of buf[cur] done; next iter may overwrite it
  }

  // l-reduction across quads; lane's own token = c -> no shuffle
  lrun += __shfl_xor(lrun, 16, 64);
  lrun += __shfl_xor(lrun, 32, 64);
  float linv = 1.0f / lrun;
  size_t row = (size_t)(b * 1024 + q0 + wq + c);
#pragma unroll
  for (int ntd = 0; ntd < 4; ntd++) {
    int d0 = ntd * 16 + quad * 4;
    u16x4 pk;
#pragma unroll
    for (int r = 0; r < 4; r++) pk[r] = f2bf(o[ntd][r] * linv);
    *(u16x4*)&AO[row * 1024 + head * 64 + d0] = pk;
  }
}

// ---------------------------------------------------------------------------
extern "C" void kernel_launch(void* const* d_in, const int* in_sizes, int n_in,
                              void* d_out, int out_size, void* d_ws, size_t ws_size,
                              hipStream_t stream) {
  const float* hs     = (const float*)d_in[0];
  const int*   morpho = (const int*)d_in[1];
  const float* Wq = (const float*)d_in[2];
  const float* bq = (const float*)d_in[3];
  const float* Wk = (const float*)d_in[4];
  const float* bk = (const float*)d_in[5];
  const float* Wv = (const float*)d_in[6];
  const float* bv = (const float*)d_in[7];
  const float* Wo = (const float*)d_in[8];
  const float* bo = (const float*)d_in[9];
  float* out = (float*)d_out;

  char* ws = (char*)d_ws;
  unsigned short* hsb = (unsigned short*)(ws);                    // 8 MB [4096][1024]
  unsigned short* Wt  = (unsigned short*)(ws + (8u << 20));       // 8 MB [4][1024][1024]
  unsigned short* Qb  = (unsigned short*)(ws + (16u << 20));      // Q +16MB, K +24MB
  unsigned short* Kb  = (unsigned short*)(ws + (24u << 20));
  unsigned short* Vtb = (unsigned short*)(ws + (40u << 20));      // 8 MB [B,NH,HD,S]
  float* colbias      = (float*)(ws + (48u << 20));               // 16 KB
  int*   nearestp     = (int*)(ws + (48u << 20) + (16u << 10));   // 16 KB
  unsigned short* AO  = hsb;  // reuse: hs_bf16 dead after QKV GEMM

  k_prep<<<3088, 256, 0, stream>>>(hs, hsb, Wq, Wk, Wv, Wo, Wt, morpho,
                                   colbias, nearestp);
  k_gemm<0><<<dim3(24, 32), 256, 0, stream>>>(hsb, Wt, bq, bk, bv, Qb, Vtb, nullptr);
  k_attn<<<dim3(64, 16), 256, 0, stream>>>(Qb, Kb, Vtb, colbias, nearestp, AO);
  k_gemm<1><<<dim3(8, 64), 256, 0, stream>>>(AO, Wt + 3 * 1048576, bo, nullptr, nullptr,
                                             nullptr, nullptr, out);
  (void)in_sizes; (void)n_in; (void)out_size; (void)ws_size; (void)Kb;
}